// Round 1
// baseline (1305.046 us; speedup 1.0000x reference)
//
#include <hip/hip_runtime.h>
#include <math.h>

#define BB 16
#define NN_ 1024
#define FF 3
#define TT 12
#define KK 3
#define CC 64

// ---------------- workspace layout (floats) ----------------
// acc[0]=sum, acc[1]=sumsq, acc[2]=mu, acc[3]=inv_std
static const size_t ACC_OFF    = 0;          // 16
static const size_t COLSUM_OFF = 16;         // B*N = 16384
static const size_t TAT_OFF    = 16400;      // B*T*T = 2304
static const size_t LHST_OFF   = 18704;      // B*N*T = 196608
static const size_t RHS2_OFF   = 215312;     // B*T*N = 196608
static const size_t SIG2_OFF   = 411920;     // B*N*N = 16777216
static const size_t S_OFF      = 17189136;   // B*N*N = 16777216
static const size_t RHSC_OFF   = 33966352;   // B*K*N*F*T = 1769472
static const size_t GCN_OFF    = SIG2_OFF;   // alias: sig2 dead after GEMM
// total: 35735824 floats = ~143 MB

__device__ __forceinline__ float wave_reduce_sum(float v) {
    #pragma unroll
    for (int off = 32; off > 0; off >>= 1) v += __shfl_down(v, off);
    return v;
}

// ---------------- init: zero acc + colsum ----------------
__global__ void k_init(float* __restrict__ ws) {
    int i = blockIdx.x * 256 + threadIdx.x;
    if (i < 16400) ws[i] = 0.f;
}

// ---------------- temporal attention -> tat (B,T,T) ----------------
// prod[t,u] = sum_f lhsA[f,t] * M[f,u],
// lhsA[f,t] = sum_n x[b,n,f,t]*U1[n],
// M[f,u]    = sum_n U2[f,n] * (sum_f' x[b,n,f',u]*U3[f'])
__global__ __launch_bounds__(64) void k_temporal(
    const float* __restrict__ x, const float* __restrict__ U1,
    const float* __restrict__ U2, const float* __restrict__ U3,
    const float* __restrict__ be, const float* __restrict__ Ve,
    float* __restrict__ tat)
{
    const int b = blockIdx.x;
    const int lane = threadIdx.x;
    float lA[36], lM[36];
    #pragma unroll
    for (int i = 0; i < 36; ++i) { lA[i] = 0.f; lM[i] = 0.f; }
    const float u30 = U3[0], u31 = U3[1], u32 = U3[2];
    for (int n = lane; n < NN_; n += 64) {
        const float* xp = x + ((size_t)b * NN_ + n) * 36;
        float xr[36];
        #pragma unroll
        for (int i = 0; i < 9; ++i) *(float4*)&xr[i*4] = *(const float4*)(xp + i*4);
        const float u1  = U1[n];
        const float u20 = U2[n], u21 = U2[NN_ + n], u22 = U2[2*NN_ + n];
        #pragma unroll
        for (int t = 0; t < 12; ++t) {
            float ru = xr[t]*u30 + xr[12+t]*u31 + xr[24+t]*u32;
            lM[t]    += u20 * ru;
            lM[12+t] += u21 * ru;
            lM[24+t] += u22 * ru;
            lA[t]    += xr[t]    * u1;
            lA[12+t] += xr[12+t] * u1;
            lA[24+t] += xr[24+t] * u1;
        }
    }
    __shared__ float tA[36], tM[36], sgs[144], es[144], cmax[12], csum[12];
    #pragma unroll
    for (int i = 0; i < 36; ++i) {
        float v = wave_reduce_sum(lA[i]);
        if (lane == 0) tA[i] = v;
        float w = wave_reduce_sum(lM[i]);
        if (lane == 0) tM[i] = w;
    }
    __syncthreads();
    for (int idx = lane; idx < 144; idx += 64) {
        int t = idx / 12, u = idx % 12;
        float p = tA[t]*tM[u] + tA[12+t]*tM[12+u] + tA[24+t]*tM[24+u];
        p += be[idx];
        sgs[idx] = 1.f / (1.f + expf(-p));
    }
    __syncthreads();
    for (int idx = lane; idx < 144; idx += 64) {
        int i = idx / 12, j = idx % 12;
        float e = 0.f;
        #pragma unroll
        for (int k = 0; k < 12; ++k) e += sgs[i*12 + k] * Ve[j*12 + k];
        es[idx] = e;
    }
    __syncthreads();
    if (lane < 12) {
        int j = lane;
        float m = -1e30f;
        for (int i = 0; i < 12; ++i) m = fmaxf(m, es[i*12 + j]);
        float sx = 0.f;
        for (int i = 0; i < 12; ++i) sx += expf(es[i*12 + j] - m);
        cmax[j] = m; csum[j] = sx;
    }
    __syncthreads();
    for (int idx = lane; idx < 144; idx += 64) {
        int j = idx % 12;
        tat[(size_t)b*144 + idx] = expf(es[idx] - cmax[j]) / csum[j];
    }
}

// ---------------- x_tat projections -> lhsT (B,N,T), rhs2 (B,T,N) ----------------
__global__ __launch_bounds__(256) void k_xtat(
    const float* __restrict__ x, const float* __restrict__ tat,
    const float* __restrict__ W1, const float* __restrict__ W2,
    const float* __restrict__ W3,
    float* __restrict__ lhsT, float* __restrict__ rhs2)
{
    const int id = blockIdx.x * 256 + threadIdx.x;   // 0..B*N-1
    const int b = id >> 10, n = id & 1023;
    const float* xp = x + (size_t)id * 36;
    float xr[36];
    #pragma unroll
    for (int i = 0; i < 9; ++i) *(float4*)&xr[i*4] = *(const float4*)(xp + i*4);
    const float* tp = tat + (size_t)b * 144;
    float xt[36];
    #pragma unroll
    for (int f = 0; f < 3; ++f)
        #pragma unroll
        for (int u = 0; u < 12; ++u) {
            float s = 0.f;
            #pragma unroll
            for (int t = 0; t < 12; ++t) s += xr[f*12 + t] * tp[t*12 + u];
            xt[f*12 + u] = s;
        }
    float lA0 = 0.f, lA1 = 0.f, lA2 = 0.f;
    #pragma unroll
    for (int t = 0; t < 12; ++t) {
        float w = W1[t];
        lA0 += xt[t]*w; lA1 += xt[12+t]*w; lA2 += xt[24+t]*w;
    }
    #pragma unroll
    for (int t2 = 0; t2 < 12; ++t2)
        lhsT[(size_t)id*12 + t2] = lA0*W2[t2] + lA1*W2[12+t2] + lA2*W2[24+t2];
    const float w30 = W3[0], w31 = W3[1], w32 = W3[2];
    #pragma unroll
    for (int u = 0; u < 12; ++u)
        rhs2[((size_t)b*12 + u)*NN_ + n] = xt[u]*w30 + xt[12+u]*w31 + xt[24+u]*w32;
}

// ---------------- sig2 (B,N,N) ----------------
__global__ __launch_bounds__(256) void k_sig2(
    const float* __restrict__ lhsT, const float* __restrict__ rhs2,
    const float* __restrict__ bs, float* __restrict__ sig2)
{
    const unsigned int idx = blockIdx.x * 256u + threadIdx.x;
    const int m = (int)(idx & 1023u);
    const unsigned int bn = idx >> 10;
    const int n = (int)(bn & 1023u);
    const int b = (int)(bn >> 10);
    const float* lp = lhsT + (size_t)bn * 12;
    const float* rp = rhs2 + (size_t)b * 12 * NN_ + m;
    float z = bs[(size_t)n * NN_ + m];
    #pragma unroll
    for (int t = 0; t < 12; ++t) z += lp[t] * rp[(size_t)t * NN_];
    sig2[idx] = 1.f / (1.f + expf(-z));
}

// ---------------- s[b] = sig2[b] @ V_s^T  (fp32 NT GEMM, 128x128 tile) ----------------
__global__ __launch_bounds__(256) void k_gemm_s(
    const float* __restrict__ A, const float* __restrict__ Vw,
    float* __restrict__ S)
{
    __shared__ float As[16][132];
    __shared__ float Bs[16][132];
    const int b  = blockIdx.z;
    const int i0 = blockIdx.y * 128;
    const int j0 = blockIdx.x * 128;
    const int tid = threadIdx.x;
    const int tx = tid & 15;          // 0..15
    const int ty = tid >> 4;          // 0..15
    const int lr = tid >> 2;          // 0..63
    const int lk = (tid & 3) << 2;    // 0,4,8,12
    const float* Ab = A + (size_t)b * NN_ * NN_;
    float acc[8][8];
    #pragma unroll
    for (int p = 0; p < 8; ++p)
        #pragma unroll
        for (int q = 0; q < 8; ++q) acc[p][q] = 0.f;

    for (int k0 = 0; k0 < NN_; k0 += 16) {
        float4 a0 = *(const float4*)(Ab + (size_t)(i0 + lr)      * NN_ + k0 + lk);
        float4 a1 = *(const float4*)(Ab + (size_t)(i0 + 64 + lr) * NN_ + k0 + lk);
        float4 b0 = *(const float4*)(Vw + (size_t)(j0 + lr)      * NN_ + k0 + lk);
        float4 b1 = *(const float4*)(Vw + (size_t)(j0 + 64 + lr) * NN_ + k0 + lk);
        As[lk+0][lr] = a0.x; As[lk+1][lr] = a0.y; As[lk+2][lr] = a0.z; As[lk+3][lr] = a0.w;
        As[lk+0][64+lr] = a1.x; As[lk+1][64+lr] = a1.y; As[lk+2][64+lr] = a1.z; As[lk+3][64+lr] = a1.w;
        Bs[lk+0][lr] = b0.x; Bs[lk+1][lr] = b0.y; Bs[lk+2][lr] = b0.z; Bs[lk+3][lr] = b0.w;
        Bs[lk+0][64+lr] = b1.x; Bs[lk+1][64+lr] = b1.y; Bs[lk+2][64+lr] = b1.z; Bs[lk+3][64+lr] = b1.w;
        __syncthreads();
        #pragma unroll
        for (int kk = 0; kk < 16; ++kk) {
            float av[8], bv[8];
            *(float4*)&av[0] = *(const float4*)&As[kk][ty*8];
            *(float4*)&av[4] = *(const float4*)&As[kk][ty*8 + 4];
            *(float4*)&bv[0] = *(const float4*)&Bs[kk][tx*8];
            *(float4*)&bv[4] = *(const float4*)&Bs[kk][tx*8 + 4];
            #pragma unroll
            for (int p = 0; p < 8; ++p)
                #pragma unroll
                for (int q = 0; q < 8; ++q)
                    acc[p][q] += av[p] * bv[q];
        }
        __syncthreads();
    }
    float* Sp = S + (size_t)b * NN_ * NN_;
    #pragma unroll
    for (int p = 0; p < 8; ++p) {
        float* row = Sp + (size_t)(i0 + ty*8 + p) * NN_ + j0 + tx*8;
        *(float4*)(row)     = make_float4(acc[p][0], acc[p][1], acc[p][2], acc[p][3]);
        *(float4*)(row + 4) = make_float4(acc[p][4], acc[p][5], acc[p][6], acc[p][7]);
    }
}

// ---------------- softmax over axis1 (rows i), per (b, j) column ----------------
__global__ __launch_bounds__(256) void k_colsum(
    const float* __restrict__ S, float* __restrict__ colsum)
{
    const int j  = blockIdx.x * 256 + threadIdx.x;
    const int b  = blockIdx.z;
    const int i0 = blockIdx.y * 128;
    const float* Sp = S + (size_t)b * NN_ * NN_ + (size_t)i0 * NN_ + j;
    float loc = 0.f;
    for (int ii = 0; ii < 128; ++ii) loc += expf(Sp[(size_t)ii * NN_]);
    atomicAdd(&colsum[b * NN_ + j], loc);
}

__global__ __launch_bounds__(256) void k_satnorm(
    float* __restrict__ S, const float* __restrict__ colsum)
{
    const unsigned int idx = blockIdx.x * 256u + threadIdx.x;
    const int j = (int)(idx & 1023u);
    const int b = (int)(idx >> 20);
    S[idx] = expf(S[idx]) / colsum[b * NN_ + j];
}

// ---------------- rhs_c[b,k,m,f,t] = sum_n cheb[k,n,m]*sat[b,n,m]*x[b,n,f,t] ----------------
__global__ __launch_bounds__(256) void k_rhsc(
    const float* __restrict__ cheb, const float* __restrict__ sat,
    const float* __restrict__ x, float* __restrict__ rhsc)
{
    __shared__ float ch[16][64];
    __shared__ float st[16][64];
    __shared__ float xt[16][36];
    const int m0 = blockIdx.x * 64;
    const int k  = blockIdx.y;
    const int b  = blockIdx.z;
    const int tid = threadIdx.x;
    const int m = tid >> 2, q = tid & 3;
    const int nn = tid >> 4, mm = (tid & 15) << 2;
    const float* cb = cheb + (size_t)k * NN_ * NN_;
    const float* sb = sat  + (size_t)b * NN_ * NN_;
    const float* xb = x    + (size_t)b * NN_ * 36;
    float acc[9];
    #pragma unroll
    for (int jj = 0; jj < 9; ++jj) acc[jj] = 0.f;
    for (int n0 = 0; n0 < NN_; n0 += 16) {
        *(float4*)&ch[nn][mm] = *(const float4*)(cb + (size_t)(n0 + nn) * NN_ + m0 + mm);
        *(float4*)&st[nn][mm] = *(const float4*)(sb + (size_t)(n0 + nn) * NN_ + m0 + mm);
        if (tid < 144) {
            int n2 = tid / 9, q2 = tid - n2 * 9;
            *(float4*)&xt[n2][q2*4] = *(const float4*)(xb + (size_t)(n0 + n2) * 36 + q2*4);
        }
        __syncthreads();
        #pragma unroll
        for (int u = 0; u < 16; ++u) {
            float w = ch[u][m] * st[u][m];
            #pragma unroll
            for (int jj = 0; jj < 9; ++jj) acc[jj] += w * xt[u][q*9 + jj];
        }
        __syncthreads();
    }
    float* rp = rhsc + (((size_t)b*3 + k) * NN_ + m0 + m) * 36 + q*9;
    #pragma unroll
    for (int jj = 0; jj < 9; ++jj) rp[jj] = acc[jj];
}

// ---------------- gcn[b,m,c,t] = relu(sum_{k,f} rhs_c * Theta) ----------------
__global__ __launch_bounds__(256) void k_gcn(
    const float* __restrict__ rhsc, const float* __restrict__ Theta,
    float* __restrict__ gcn)
{
    const unsigned int idx = blockIdx.x * 256u + threadIdx.x;
    const int t = (int)(idx % 12u);
    const unsigned int r = idx / 12u;
    const int c = (int)(r & 63u);
    const unsigned int bm = r >> 6;
    const int m = (int)(bm & 1023u);
    const int b = (int)(bm >> 10);
    float acc = 0.f;
    #pragma unroll
    for (int k = 0; k < 3; ++k) {
        const float* rp = rhsc + (((size_t)b*3 + k) * NN_ + m) * 36 + t;
        const float* tp = Theta + k*192 + c;
        #pragma unroll
        for (int f = 0; f < 3; ++f) acc += rp[f*12] * tp[f*64];
    }
    gcn[idx] = fmaxf(acc, 0.f);
}

// ---------------- tconv + residual + relu + partial sums -> y (= d_out) ----------------
__global__ __launch_bounds__(64) void k_y(
    const float* __restrict__ gcn, const float* __restrict__ x,
    const float* __restrict__ tcw, const float* __restrict__ tcb,
    const float* __restrict__ rcw, const float* __restrict__ rcb,
    float* __restrict__ y, float* __restrict__ acc)
{
    __shared__ float g[64][12];
    __shared__ float xs[36];
    const int bn = blockIdx.x;
    const int lane = threadIdx.x;
    const float* gp = gcn + (size_t)bn * 768;
    {
        const float4* s4 = (const float4*)(gp + lane * 12);
        float4 v0 = s4[0], v1 = s4[1], v2 = s4[2];
        float* d = &g[lane][0];
        *(float4*)d = v0; *(float4*)(d + 4) = v1; *(float4*)(d + 8) = v2;
    }
    if (lane < 9)
        *(float4*)&xs[lane*4] = *(const float4*)(x + (size_t)bn * 36 + lane*4);
    __syncthreads();
    const int c = lane;
    float tco[12];
    const float tb = tcb[c];
    #pragma unroll
    for (int t = 0; t < 12; ++t) tco[t] = tb;
    const float* wp = tcw + c * 192;
    for (int cp0 = 0; cp0 < 64; cp0 += 4) {
        float wv[12];
        *(float4*)&wv[0] = *(const float4*)(wp + cp0*3);
        *(float4*)&wv[4] = *(const float4*)(wp + cp0*3 + 4);
        *(float4*)&wv[8] = *(const float4*)(wp + cp0*3 + 8);
        #pragma unroll
        for (int cc = 0; cc < 4; ++cc) {
            const int cp = cp0 + cc;
            const float w0 = wv[cc*3], w1 = wv[cc*3+1], w2 = wv[cc*3+2];
            float gv[12];
            #pragma unroll
            for (int t = 0; t < 12; ++t) gv[t] = g[cp][t];
            tco[0]  += gv[0]*w1 + gv[1]*w2;
            #pragma unroll
            for (int t = 1; t < 11; ++t)
                tco[t] += gv[t-1]*w0 + gv[t]*w1 + gv[t+1]*w2;
            tco[11] += gv[10]*w0 + gv[11]*w1;
        }
    }
    const float r0 = rcw[c*3], r1 = rcw[c*3+1], r2 = rcw[c*3+2];
    const float rb = rcb[c];
    float ls = 0.f, lss = 0.f;
    float yv[12];
    #pragma unroll
    for (int t = 0; t < 12; ++t) {
        float xres = rb + xs[t]*r0 + xs[12+t]*r1 + xs[24+t]*r2;
        float v = fmaxf(xres + tco[t], 0.f);
        yv[t] = v; ls += v; lss += v * v;
    }
    float* yp = y + (size_t)bn * 768 + c * 12;
    *(float4*)(yp)     = make_float4(yv[0], yv[1], yv[2],  yv[3]);
    *(float4*)(yp + 4) = make_float4(yv[4], yv[5], yv[6],  yv[7]);
    *(float4*)(yp + 8) = make_float4(yv[8], yv[9], yv[10], yv[11]);
    ls  = wave_reduce_sum(ls);
    lss = wave_reduce_sum(lss);
    if (lane == 0) { atomicAdd(&acc[0], ls); atomicAdd(&acc[1], lss); }
}

// ---------------- finalize mean / inv_std ----------------
__global__ void k_fin(float* __restrict__ acc) {
    const float cnt = (float)((size_t)BB * NN_ * CC * TT);
    float mu = acc[0] / cnt;
    float var = acc[1] / cnt - mu * mu;
    acc[2] = mu;
    acc[3] = rsqrtf(var + 1e-5f);
}

// ---------------- normalize in place on d_out ----------------
__global__ __launch_bounds__(256) void k_norm(
    float* __restrict__ y, const float* __restrict__ lng,
    const float* __restrict__ lnb, const float* __restrict__ acc)
{
    const unsigned int i = blockIdx.x * 256u + threadIdx.x;
    const float mu = acc[2], inv = acc[3];
    float4 v  = ((const float4*)y)[i];
    float4 gv = ((const float4*)lng)[i];
    float4 bv = ((const float4*)lnb)[i];
    v.x = (v.x - mu) * inv * gv.x + bv.x;
    v.y = (v.y - mu) * inv * gv.y + bv.y;
    v.z = (v.z - mu) * inv * gv.z + bv.z;
    v.w = (v.w - mu) * inv * gv.w + bv.w;
    ((float4*)y)[i] = v;
}

extern "C" void kernel_launch(void* const* d_in, const int* in_sizes, int n_in,
                              void* d_out, int out_size, void* d_ws, size_t ws_size,
                              hipStream_t stream)
{
    const float* x    = (const float*)d_in[0];
    const float* U1   = (const float*)d_in[1];
    const float* U2   = (const float*)d_in[2];
    const float* U3   = (const float*)d_in[3];
    const float* be   = (const float*)d_in[4];
    const float* Ve   = (const float*)d_in[5];
    const float* W1   = (const float*)d_in[6];
    const float* W2   = (const float*)d_in[7];
    const float* W3   = (const float*)d_in[8];
    const float* bs   = (const float*)d_in[9];
    const float* Vs   = (const float*)d_in[10];
    const float* cheb = (const float*)d_in[11];
    const float* Th   = (const float*)d_in[12];
    const float* tcw  = (const float*)d_in[13];
    const float* tcb  = (const float*)d_in[14];
    const float* rcw  = (const float*)d_in[15];
    const float* rcb  = (const float*)d_in[16];
    const float* lng  = (const float*)d_in[17];
    const float* lnb  = (const float*)d_in[18];
    float* out = (float*)d_out;
    float* ws  = (float*)d_ws;

    float* acc    = ws + ACC_OFF;
    float* colsum = ws + COLSUM_OFF;
    float* tat    = ws + TAT_OFF;
    float* lhsT   = ws + LHST_OFF;
    float* rhs2   = ws + RHS2_OFF;
    float* sig2   = ws + SIG2_OFF;
    float* S      = ws + S_OFF;
    float* rhsc   = ws + RHSC_OFF;
    float* gcn    = ws + GCN_OFF;

    k_init<<<65, 256, 0, stream>>>(ws);
    k_temporal<<<BB, 64, 0, stream>>>(x, U1, U2, U3, be, Ve, tat);
    k_xtat<<<(BB * NN_) / 256, 256, 0, stream>>>(x, tat, W1, W2, W3, lhsT, rhs2);
    k_sig2<<<(BB * NN_ * NN_) / 256, 256, 0, stream>>>(lhsT, rhs2, bs, sig2);
    k_gemm_s<<<dim3(8, 8, BB), 256, 0, stream>>>(sig2, Vs, S);
    k_colsum<<<dim3(4, 8, BB), 256, 0, stream>>>(S, colsum);
    k_satnorm<<<(BB * NN_ * NN_) / 256, 256, 0, stream>>>(S, colsum);
    k_rhsc<<<dim3(16, 3, BB), 256, 0, stream>>>(cheb, S, x, rhsc);
    k_gcn<<<(BB * NN_ * CC * TT) / 256, 256, 0, stream>>>(rhsc, Th, gcn);
    k_y<<<BB * NN_, 64, 0, stream>>>(gcn, x, tcw, tcb, rcw, rcb, out, acc);
    k_fin<<<1, 1, 0, stream>>>(acc);
    k_norm<<<(BB * NN_ * CC * TT) / 4 / 256, 256, 0, stream>>>(out, lng, lnb, acc);
}

// Round 2
// 700.924 us; speedup vs baseline: 1.8619x; 1.8619x over previous
//
#include <hip/hip_runtime.h>
#include <hip/hip_bf16.h>
#include <math.h>

#define BB 16
#define NN_ 1024
#define TT 12

typedef __attribute__((ext_vector_type(8))) short bf16x8;
typedef __attribute__((ext_vector_type(4))) float f32x4;

// ---------------- workspace layout (float units) ----------------
static const size_t ACC_OFF    = 0;          // 16
static const size_t COLSUM_OFF = 16;         // B*N = 16384
static const size_t TAT_OFF    = 16400;      // B*T*T = 2304
static const size_t LHST_OFF   = 18704;      // B*N*T = 196608
static const size_t RHS2_OFF   = 215312;     // B*T*N = 196608
static const size_t VSB_OFF    = 411920;     // N*N bf16 = 524288 floats
static const size_t SIG2B_OFF  = 936208;     // B*N*N bf16 = 8388608 floats
static const size_t S_OFF      = 9324816;    // B*N*N fp32 = 16777216
static const size_t RHSC_OFF   = 26102032;   // B*K*N*F*T = 1769472
// total 27871504 floats = ~112 MB

__device__ __forceinline__ float wave_reduce_sum(float v) {
    #pragma unroll
    for (int off = 32; off > 0; off >>= 1) v += __shfl_down(v, off);
    return v;
}

// ---------------- init: zero acc + colsum ----------------
__global__ void k_init(float* __restrict__ ws) {
    int i = blockIdx.x * 256 + threadIdx.x;
    if (i < 16400) ws[i] = 0.f;
}

// ---------------- temporal attention -> tat (B,T,T) ----------------
__global__ __launch_bounds__(64) void k_temporal(
    const float* __restrict__ x, const float* __restrict__ U1,
    const float* __restrict__ U2, const float* __restrict__ U3,
    const float* __restrict__ be, const float* __restrict__ Ve,
    float* __restrict__ tat)
{
    const int b = blockIdx.x;
    const int lane = threadIdx.x;
    float lA[36], lM[36];
    #pragma unroll
    for (int i = 0; i < 36; ++i) { lA[i] = 0.f; lM[i] = 0.f; }
    const float u30 = U3[0], u31 = U3[1], u32 = U3[2];
    for (int n = lane; n < NN_; n += 64) {
        const float* xp = x + ((size_t)b * NN_ + n) * 36;
        float xr[36];
        #pragma unroll
        for (int i = 0; i < 9; ++i) *(float4*)&xr[i*4] = *(const float4*)(xp + i*4);
        const float u1  = U1[n];
        const float u20 = U2[n], u21 = U2[NN_ + n], u22 = U2[2*NN_ + n];
        #pragma unroll
        for (int t = 0; t < 12; ++t) {
            float ru = xr[t]*u30 + xr[12+t]*u31 + xr[24+t]*u32;
            lM[t]    += u20 * ru;
            lM[12+t] += u21 * ru;
            lM[24+t] += u22 * ru;
            lA[t]    += xr[t]    * u1;
            lA[12+t] += xr[12+t] * u1;
            lA[24+t] += xr[24+t] * u1;
        }
    }
    __shared__ float tA[36], tM[36], sgs[144], es[144], cmax[12], csum[12];
    #pragma unroll
    for (int i = 0; i < 36; ++i) {
        float v = wave_reduce_sum(lA[i]);
        if (lane == 0) tA[i] = v;
        float w = wave_reduce_sum(lM[i]);
        if (lane == 0) tM[i] = w;
    }
    __syncthreads();
    for (int idx = lane; idx < 144; idx += 64) {
        int t = idx / 12, u = idx % 12;
        float p = tA[t]*tM[u] + tA[12+t]*tM[12+u] + tA[24+t]*tM[24+u];
        p += be[idx];
        sgs[idx] = 1.f / (1.f + expf(-p));
    }
    __syncthreads();
    for (int idx = lane; idx < 144; idx += 64) {
        int i = idx / 12, j = idx % 12;
        float e = 0.f;
        #pragma unroll
        for (int k = 0; k < 12; ++k) e += sgs[i*12 + k] * Ve[j*12 + k];
        es[idx] = e;
    }
    __syncthreads();
    if (lane < 12) {
        int j = lane;
        float m = -1e30f;
        for (int i = 0; i < 12; ++i) m = fmaxf(m, es[i*12 + j]);
        float sx = 0.f;
        for (int i = 0; i < 12; ++i) sx += expf(es[i*12 + j] - m);
        cmax[j] = m; csum[j] = sx;
    }
    __syncthreads();
    for (int idx = lane; idx < 144; idx += 64) {
        int j = idx % 12;
        tat[(size_t)b*144 + idx] = expf(es[idx] - cmax[j]) / csum[j];
    }
}

// ---------------- x_tat projections -> lhsT (B,N,T), rhs2 (B,T,N) ----------------
__global__ __launch_bounds__(256) void k_xtat(
    const float* __restrict__ x, const float* __restrict__ tat,
    const float* __restrict__ W1, const float* __restrict__ W2,
    const float* __restrict__ W3,
    float* __restrict__ lhsT, float* __restrict__ rhs2)
{
    const int id = blockIdx.x * 256 + threadIdx.x;
    const int b = id >> 10, n = id & 1023;
    const float* xp = x + (size_t)id * 36;
    float xr[36];
    #pragma unroll
    for (int i = 0; i < 9; ++i) *(float4*)&xr[i*4] = *(const float4*)(xp + i*4);
    const float* tp = tat + (size_t)b * 144;
    float xt[36];
    #pragma unroll
    for (int f = 0; f < 3; ++f)
        #pragma unroll
        for (int u = 0; u < 12; ++u) {
            float s = 0.f;
            #pragma unroll
            for (int t = 0; t < 12; ++t) s += xr[f*12 + t] * tp[t*12 + u];
            xt[f*12 + u] = s;
        }
    float lA0 = 0.f, lA1 = 0.f, lA2 = 0.f;
    #pragma unroll
    for (int t = 0; t < 12; ++t) {
        float w = W1[t];
        lA0 += xt[t]*w; lA1 += xt[12+t]*w; lA2 += xt[24+t]*w;
    }
    #pragma unroll
    for (int t2 = 0; t2 < 12; ++t2)
        lhsT[(size_t)id*12 + t2] = lA0*W2[t2] + lA1*W2[12+t2] + lA2*W2[24+t2];
    const float w30 = W3[0], w31 = W3[1], w32 = W3[2];
    #pragma unroll
    for (int u = 0; u < 12; ++u)
        rhs2[((size_t)b*12 + u)*NN_ + n] = xt[u]*w30 + xt[12+u]*w31 + xt[24+u]*w32;
}

// ---------------- sig2 (B,N,N) -> bf16 ----------------
__global__ __launch_bounds__(256) void k_sig2(
    const float* __restrict__ lhsT, const float* __restrict__ rhs2,
    const float* __restrict__ bs, __hip_bfloat16* __restrict__ sig2b)
{
    const unsigned int idx = blockIdx.x * 256u + threadIdx.x;
    const int m = (int)(idx & 1023u);
    const unsigned int bn = idx >> 10;
    const int b = (int)(bn >> 10);
    const int n = (int)(bn & 1023u);
    const float* lp = lhsT + (size_t)bn * 12;
    const float* rp = rhs2 + (size_t)b * 12 * NN_ + m;
    float z = bs[(size_t)n * NN_ + m];
    #pragma unroll
    for (int t = 0; t < 12; ++t) z += lp[t] * rp[(size_t)t * NN_];
    sig2b[idx] = __float2bfloat16(1.f / (1.f + expf(-z)));
}

// ---------------- Vs -> bf16 ----------------
__global__ __launch_bounds__(256) void k_cvt_vs(
    const float* __restrict__ Vs, __hip_bfloat16* __restrict__ Vsb)
{
    const int i = blockIdx.x * 256 + threadIdx.x;
    Vsb[i] = __float2bfloat16(Vs[i]);
}

// ---------------- S[b] = sig2[b] @ Vs^T  (bf16 MFMA NT GEMM) ----------------
__global__ __launch_bounds__(256) void k_gemm_s_mfma(
    const short* __restrict__ A,   // sig2b [B][1024][1024] bf16
    const short* __restrict__ Bm,  // Vsb   [1024][1024] bf16 (row j, k-contig)
    float* __restrict__ S)
{
    __shared__ short As[128 * 32];
    __shared__ short Bs[128 * 32];
    const int b  = blockIdx.z;
    const int i0 = blockIdx.y * 128;
    const int j0 = blockIdx.x * 128;
    const int tid = threadIdx.x;
    const int wid = tid >> 6;
    const int lane = tid & 63;
    const int wr = wid & 1, wc = wid >> 1;
    const short* Ab = A + (size_t)b * NN_ * NN_;

    f32x4 acc[4][4];
    const f32x4 z4 = {0.f, 0.f, 0.f, 0.f};
    #pragma unroll
    for (int m = 0; m < 4; ++m)
        #pragma unroll
        for (int n = 0; n < 4; ++n) acc[m][n] = z4;

    const int srow = lane >> 2;     // 0..15
    const int schk = lane & 3;      // 0..3
    const int fr = lane & 15;
    const int kb = (lane >> 4) * 8;

    for (int k0 = 0; k0 < NN_; k0 += 32) {
        #pragma unroll
        for (int q = 0; q < 2; ++q) {
            const int rb = (wid * 2 + q) * 16;
            const short* srcA = Ab + (size_t)(i0 + rb + srow) * NN_ + k0 + schk * 8;
            const short* srcB = Bm + (size_t)(j0 + rb + srow) * NN_ + k0 + schk * 8;
            __builtin_amdgcn_global_load_lds(
                (const __attribute__((address_space(1))) unsigned int*)srcA,
                (__attribute__((address_space(3))) unsigned int*)(As + rb * 32), 16, 0, 0);
            __builtin_amdgcn_global_load_lds(
                (const __attribute__((address_space(1))) unsigned int*)srcB,
                (__attribute__((address_space(3))) unsigned int*)(Bs + rb * 32), 16, 0, 0);
        }
        __syncthreads();
        bf16x8 aF[4], bF[4];
        #pragma unroll
        for (int m = 0; m < 4; ++m)
            aF[m] = *(const bf16x8*)(As + (wr*64 + m*16 + fr) * 32 + kb);
        #pragma unroll
        for (int n = 0; n < 4; ++n)
            bF[n] = *(const bf16x8*)(Bs + (wc*64 + n*16 + fr) * 32 + kb);
        #pragma unroll
        for (int m = 0; m < 4; ++m)
            #pragma unroll
            for (int n = 0; n < 4; ++n)
                acc[m][n] = __builtin_amdgcn_mfma_f32_16x16x32_bf16(aF[m], bF[n], acc[m][n], 0, 0, 0);
        __syncthreads();
    }
    float* Sp = S + (size_t)b * NN_ * NN_;
    const int cn = lane & 15;
    const int r0 = (lane >> 4) * 4;
    #pragma unroll
    for (int m = 0; m < 4; ++m)
        #pragma unroll
        for (int n = 0; n < 4; ++n)
            #pragma unroll
            for (int r = 0; r < 4; ++r)
                Sp[(size_t)(i0 + wr*64 + m*16 + r0 + r) * NN_ + j0 + wc*64 + n*16 + cn] = acc[m][n][r];
}

// ---------------- softmax over axis1 ----------------
__global__ __launch_bounds__(256) void k_colsum(
    const float* __restrict__ S, float* __restrict__ colsum)
{
    const int j  = blockIdx.x * 256 + threadIdx.x;
    const int b  = blockIdx.z;
    const int i0 = blockIdx.y * 128;
    const float* Sp = S + (size_t)b * NN_ * NN_ + (size_t)i0 * NN_ + j;
    float loc = 0.f;
    for (int ii = 0; ii < 128; ++ii) loc += expf(Sp[(size_t)ii * NN_]);
    atomicAdd(&colsum[b * NN_ + j], loc);
}

__global__ __launch_bounds__(256) void k_satnorm(
    float* __restrict__ S, const float* __restrict__ colsum)
{
    const unsigned int idx = blockIdx.x * 256u + threadIdx.x;
    const int j = (int)(idx & 1023u);
    const int b = (int)(idx >> 20);
    S[idx] = expf(S[idx]) / colsum[b * NN_ + j];
}

// ---------------- rhs_c[b,k,m,f,t] = sum_n cheb[k,n,m]*sat[b,n,m]*x[b,n,f,t] ----------------
__global__ __launch_bounds__(256) void k_rhsc(
    const float* __restrict__ cheb, const float* __restrict__ sat,
    const float* __restrict__ x, float* __restrict__ rhsc)
{
    __shared__ float ch[16][64];
    __shared__ float st[16][64];
    __shared__ float xt[16][36];
    const int m0 = blockIdx.x * 64;
    const int k  = blockIdx.y;
    const int b  = blockIdx.z;
    const int tid = threadIdx.x;
    const int m = tid >> 2, q = tid & 3;
    const int nn = tid >> 4, mm = (tid & 15) << 2;
    const float* cb = cheb + (size_t)k * NN_ * NN_;
    const float* sb = sat  + (size_t)b * NN_ * NN_;
    const float* xb = x    + (size_t)b * NN_ * 36;
    float acc[9];
    #pragma unroll
    for (int jj = 0; jj < 9; ++jj) acc[jj] = 0.f;
    for (int n0 = 0; n0 < NN_; n0 += 16) {
        *(float4*)&ch[nn][mm] = *(const float4*)(cb + (size_t)(n0 + nn) * NN_ + m0 + mm);
        *(float4*)&st[nn][mm] = *(const float4*)(sb + (size_t)(n0 + nn) * NN_ + m0 + mm);
        if (tid < 144) {
            int n2 = tid / 9, q2 = tid - n2 * 9;
            *(float4*)&xt[n2][q2*4] = *(const float4*)(xb + (size_t)(n0 + n2) * 36 + q2*4);
        }
        __syncthreads();
        #pragma unroll
        for (int u = 0; u < 16; ++u) {
            float w = ch[u][m] * st[u][m];
            #pragma unroll
            for (int jj = 0; jj < 9; ++jj) acc[jj] += w * xt[u][q*9 + jj];
        }
        __syncthreads();
    }
    float* rp = rhsc + (((size_t)b*3 + k) * NN_ + m0 + m) * 36 + q*9;
    #pragma unroll
    for (int jj = 0; jj < 9; ++jj) rp[jj] = acc[jj];
}

// ---------------- fused gcn + tconv + residual + relu + stats -> y ----------------
__global__ __launch_bounds__(256) void k_y2(
    const float* __restrict__ rhsc, const float* __restrict__ Theta,
    const float* __restrict__ x,
    const float* __restrict__ tcw, const float* __restrict__ tcb,
    const float* __restrict__ rcw, const float* __restrict__ rcb,
    float* __restrict__ y, float* __restrict__ acc)
{
    __shared__ float wlds[192 * 64];
    const int tid = threadIdx.x;
    const int wid = tid >> 6;
    const int c = tid & 63;
    // stage tcw swizzled: wlds[r*64 + ((cc + r) & 63)] = tcw[cc*192 + r]
    for (int i = tid; i < 12288; i += 256) {
        int cc = i / 192, r = i - cc * 192;
        wlds[r * 64 + ((cc + r) & 63)] = tcw[i];
    }
    float th[9];
    #pragma unroll
    for (int j = 0; j < 9; ++j) th[j] = Theta[j * 64 + c];
    const float tb = tcb[c];
    const float rw0 = rcw[c*3], rw1 = rcw[c*3+1], rw2 = rcw[c*3+2];
    const float rbv = rcb[c];
    __syncthreads();

    float ls = 0.f, lss = 0.f;
    const int item0 = blockIdx.x * 32 + wid * 8;
    for (int it = 0; it < 8; ++it) {
        const int bn = item0 + it;
        const int b = bn >> 10, n = bn & 1023;
        // gcn[c][t] in registers (relu applied)
        float g[12];
        #pragma unroll
        for (int t = 0; t < 12; ++t) g[t] = 0.f;
        #pragma unroll
        for (int k = 0; k < 3; ++k) {
            const float* rp = rhsc + (((size_t)b*3 + k) * NN_ + n) * 36;
            #pragma unroll
            for (int f = 0; f < 3; ++f) {
                float4 v0 = *(const float4*)(rp + f*12);
                float4 v1 = *(const float4*)(rp + f*12 + 4);
                float4 v2 = *(const float4*)(rp + f*12 + 8);
                const float w = th[k*3 + f];
                g[0] += v0.x*w; g[1] += v0.y*w; g[2]  += v0.z*w; g[3]  += v0.w*w;
                g[4] += v1.x*w; g[5] += v1.y*w; g[6]  += v1.z*w; g[7]  += v1.w*w;
                g[8] += v2.x*w; g[9] += v2.y*w; g[10] += v2.z*w; g[11] += v2.w*w;
            }
        }
        #pragma unroll
        for (int t = 0; t < 12; ++t) g[t] = fmaxf(g[t], 0.f);
        // tconv: broadcast g from lane cp via readlane
        float tco[12];
        #pragma unroll
        for (int t = 0; t < 12; ++t) tco[t] = tb;
        #pragma unroll 4
        for (int cp = 0; cp < 64; ++cp) {
            const int r0 = cp * 3;
            const float w0 = wlds[(r0+0)*64 + ((c + r0+0) & 63)];
            const float w1 = wlds[(r0+1)*64 + ((c + r0+1) & 63)];
            const float w2 = wlds[(r0+2)*64 + ((c + r0+2) & 63)];
            float gt[12];
            #pragma unroll
            for (int t = 0; t < 12; ++t)
                gt[t] = __int_as_float(__builtin_amdgcn_readlane(__float_as_int(g[t]), cp));
            tco[0] += gt[0]*w1 + gt[1]*w2;
            #pragma unroll
            for (int t = 1; t < 11; ++t)
                tco[t] += gt[t-1]*w0 + gt[t]*w1 + gt[t+1]*w2;
            tco[11] += gt[10]*w0 + gt[11]*w1;
        }
        // residual + relu + stats
        const float* xp = x + (size_t)bn * 36;
        float yv[12];
        #pragma unroll
        for (int t = 0; t < 12; ++t) {
            float xres = rbv + xp[t]*rw0 + xp[12+t]*rw1 + xp[24+t]*rw2;
            float v = fmaxf(xres + tco[t], 0.f);
            yv[t] = v; ls += v; lss += v * v;
        }
        float* yp = y + (size_t)bn * 768 + c * 12;
        *(float4*)(yp)     = make_float4(yv[0], yv[1], yv[2],  yv[3]);
        *(float4*)(yp + 4) = make_float4(yv[4], yv[5], yv[6],  yv[7]);
        *(float4*)(yp + 8) = make_float4(yv[8], yv[9], yv[10], yv[11]);
    }
    ls  = wave_reduce_sum(ls);
    lss = wave_reduce_sum(lss);
    if ((tid & 63) == 0) { atomicAdd(&acc[0], ls); atomicAdd(&acc[1], lss); }
}

// ---------------- finalize mean / inv_std ----------------
__global__ void k_fin(float* __restrict__ acc) {
    const float cnt = (float)((size_t)BB * NN_ * 64 * TT);
    float mu = acc[0] / cnt;
    float var = acc[1] / cnt - mu * mu;
    acc[2] = mu;
    acc[3] = rsqrtf(var + 1e-5f);
}

// ---------------- normalize in place on d_out ----------------
__global__ __launch_bounds__(256) void k_norm(
    float* __restrict__ y, const float* __restrict__ lng,
    const float* __restrict__ lnb, const float* __restrict__ acc)
{
    const unsigned int i = blockIdx.x * 256u + threadIdx.x;
    const float mu = acc[2], inv = acc[3];
    float4 v  = ((const float4*)y)[i];
    float4 gv = ((const float4*)lng)[i];
    float4 bv = ((const float4*)lnb)[i];
    v.x = (v.x - mu) * inv * gv.x + bv.x;
    v.y = (v.y - mu) * inv * gv.y + bv.y;
    v.z = (v.z - mu) * inv * gv.z + bv.z;
    v.w = (v.w - mu) * inv * gv.w + bv.w;
    ((float4*)y)[i] = v;
}

extern "C" void kernel_launch(void* const* d_in, const int* in_sizes, int n_in,
                              void* d_out, int out_size, void* d_ws, size_t ws_size,
                              hipStream_t stream)
{
    const float* x    = (const float*)d_in[0];
    const float* U1   = (const float*)d_in[1];
    const float* U2   = (const float*)d_in[2];
    const float* U3   = (const float*)d_in[3];
    const float* be   = (const float*)d_in[4];
    const float* Ve   = (const float*)d_in[5];
    const float* W1   = (const float*)d_in[6];
    const float* W2   = (const float*)d_in[7];
    const float* W3   = (const float*)d_in[8];
    const float* bs   = (const float*)d_in[9];
    const float* Vs   = (const float*)d_in[10];
    const float* cheb = (const float*)d_in[11];
    const float* Th   = (const float*)d_in[12];
    const float* tcw  = (const float*)d_in[13];
    const float* tcb  = (const float*)d_in[14];
    const float* rcw  = (const float*)d_in[15];
    const float* rcb  = (const float*)d_in[16];
    const float* lng  = (const float*)d_in[17];
    const float* lnb  = (const float*)d_in[18];
    float* out = (float*)d_out;
    float* ws  = (float*)d_ws;

    float* acc    = ws + ACC_OFF;
    float* colsum = ws + COLSUM_OFF;
    float* tat    = ws + TAT_OFF;
    float* lhsT   = ws + LHST_OFF;
    float* rhs2   = ws + RHS2_OFF;
    __hip_bfloat16* Vsb   = (__hip_bfloat16*)(ws + VSB_OFF);
    __hip_bfloat16* sig2b = (__hip_bfloat16*)(ws + SIG2B_OFF);
    float* S      = ws + S_OFF;
    float* rhsc   = ws + RHSC_OFF;

    k_init<<<65, 256, 0, stream>>>(ws);
    k_temporal<<<BB, 64, 0, stream>>>(x, U1, U2, U3, be, Ve, tat);
    k_xtat<<<(BB * NN_) / 256, 256, 0, stream>>>(x, tat, W1, W2, W3, lhsT, rhs2);
    k_cvt_vs<<<(NN_ * NN_) / 256, 256, 0, stream>>>(Vs, Vsb);
    k_sig2<<<(BB * NN_ * NN_) / 256, 256, 0, stream>>>(lhsT, rhs2, bs, sig2b);
    k_gemm_s_mfma<<<dim3(8, 8, BB), 256, 0, stream>>>((const short*)sig2b, (const short*)Vsb, S);
    k_colsum<<<dim3(4, 8, BB), 256, 0, stream>>>(S, colsum);
    k_satnorm<<<(BB * NN_ * NN_) / 256, 256, 0, stream>>>(S, colsum);
    k_rhsc<<<dim3(16, 3, BB), 256, 0, stream>>>(cheb, S, x, rhsc);
    k_y2<<<512, 256, 0, stream>>>(rhsc, Th, x, tcw, tcb, rcw, rcb, out, acc);
    k_fin<<<1, 1, 0, stream>>>(acc);
    k_norm<<<(BB * NN_ * 64 * TT) / 4 / 256, 256, 0, stream>>>(out, lng, lnb, acc);
}